// Round 12
// baseline (418.645 us; speedup 1.0000x reference)
//
#include <hip/hip_runtime.h>

#define HD 192
#define FD0 128
#define NG 256
#define BNEPS 1e-5f

#define STAT_S  1048576.0f        // 2^20 fixed-point scale for BN stats
#define STAT_IS (1.0f / 1048576.0f)
#define QS  2048.0f               // 2^11 fixed-point scale for i16 features
#define QIS (1.0f / 2048.0f)
#define POOL_S  65536.0f          // 2^16 fixed-point scale for pooling
#define POOL_IS (1.0f / 65536.0f)

typedef unsigned short u16;
typedef __attribute__((ext_vector_type(8))) short bf16x8;
typedef __attribute__((ext_vector_type(4))) float f32x4;

static inline int idiv(int a, int b) { return (a + b - 1) / b; }

__device__ __forceinline__ float b2f(u16 u) {
    unsigned int v = ((unsigned int)u) << 16;
    return __builtin_bit_cast(float, v);
}
__device__ __forceinline__ u16 f2b(float f) {
    unsigned int x = __builtin_bit_cast(unsigned int, f);
    return (u16)((x + 0x7FFFu + ((x >> 16) & 1u)) >> 16);   // RNE
}
__device__ __forceinline__ short f2q(float v) {
    return (short)__float2int_rn(fmaxf(fminf(v, 15.9f), -15.9f) * QS);
}

// async global->LDS, 16B per lane; LDS dest = uniform base + lane*16
__device__ __forceinline__ void async_cp16(const void* g, void* l) {
    __builtin_amdgcn_global_load_lds(
        (const __attribute__((address_space(1))) unsigned int*)g,
        (__attribute__((address_space(3))) unsigned int*)l, 16, 0, 0);
}

// ---------------- x fp32 -> bf16 + i16 (fused) ----------------
__global__ __launch_bounds__(256) void convert_x(const float* __restrict__ in,
    u16* __restrict__ xb, short* __restrict__ xq, int n4)
{
    const int i = blockIdx.x * 256 + threadIdx.x;
    if (i >= n4) return;
    const float4 v = ((const float4*)in)[i];
    u16 o[4] = { f2b(v.x), f2b(v.y), f2b(v.z), f2b(v.w) };
    ((ushort4*)xb)[i] = *(ushort4*)o;
    short q[4] = { f2q(v.x), f2q(v.y), f2q(v.z), f2q(v.w) };
    ((short4*)xq)[i] = *(short4*)q;
}

// ------- pack [Wr | Wt] bf16, MFMA-frag chunk order: [chunk][f12][kg][c][j] ---
__device__ __forceinline__ void pack_one(const float* __restrict__ wr,
    const float* __restrict__ wt, u16* __restrict__ out, int K, int idx)
{
    const int j  = idx & 7;
    const int t  = idx >> 3;
    const int c  = t & 15;
    const int kg = (t >> 4) & 3;
    const int rest = t >> 6;
    const int fglob = rest % 12;
    const int chunk = rest / 12;
    const int col = fglob * 16 + c;
    const int k   = chunk * 32 + kg * 8 + j;
    const float v = (k < K) ? wr[(size_t)col * K + k] : wt[(size_t)col * K + (k - K)];
    out[idx] = f2b(v);
}

// all 4 layers' weight packs in one launch
__global__ __launch_bounds__(256) void pack_all(const float* __restrict__ wr0,
    const float* __restrict__ wt0, const float* __restrict__ w_rel,
    const float* __restrict__ w_root, u16* __restrict__ wp0,
    u16* __restrict__ wp123)
{
    const int T0 = HD * 2 * FD0;     // 49152
    const int T1 = HD * 2 * HD;      // 73728
    int idx = blockIdx.x * 256 + threadIdx.x;
    if (idx < T0) {
        pack_one(wr0, wt0, wp0, FD0, idx);
    } else {
        idx -= T0;
        if (idx >= 3 * T1) return;
        const int li = idx / T1;
        const int r  = idx - li * T1;
        pack_one(w_rel + (size_t)li * HD * HD, w_root + (size_t)li * HD * HD,
                 wp123 + (size_t)li * T1, HD, r);
    }
}

// ------- both head transposes in one launch: wt[k][t] = w[t][k] ------
__global__ __launch_bounds__(256) void transpose_all(const float* __restrict__ w1,
    const float* __restrict__ w2, float* __restrict__ w1t, float* __restrict__ w2t)
{
    int idx = blockIdx.x * 256 + threadIdx.x;
    const float* w = w1; float* o = w1t;
    if (idx >= HD * HD) { idx -= HD * HD; w = w2; o = w2t; }
    if (idx >= HD * HD) return;
    const int t = idx % HD, k = idx / HD;
    o[idx] = w[(size_t)t * HD + k];
}

// ---------------- CSR build ----------------
__global__ __launch_bounds__(256) void hist_kernel(const int* __restrict__ dst,
                                                   int* __restrict__ deg, int E)
{
    const int e = blockIdx.x * 256 + threadIdx.x;
    if (e < E) atomicAdd(&deg[dst[e]], 1);
}

__global__ __launch_bounds__(256) void scan_partial(const int* __restrict__ deg,
                                                    int* __restrict__ psum, int N)
{
    __shared__ int s[256];
    const int t = threadIdx.x;
    const int i = blockIdx.x * 256 + t;
    s[t] = (i < N) ? deg[i] : 0;
    __syncthreads();
    for (int off = 128; off > 0; off >>= 1) {
        if (t < off) s[t] += s[t + off];
        __syncthreads();
    }
    if (t == 0) psum[blockIdx.x] = s[0];
}

__global__ __launch_bounds__(256) void scan_small(int* __restrict__ psum, int M)
{
    __shared__ int s[256];
    const int t = threadIdx.x;
    s[t] = (t < M) ? psum[t] : 0;
    __syncthreads();
    for (int off = 1; off < 256; off <<= 1) {
        const int u = (t >= off) ? s[t - off] : 0;
        __syncthreads();
        s[t] += u;
        __syncthreads();
    }
    if (t < M) psum[t] = (t == 0) ? 0 : s[t - 1];
}

__global__ __launch_bounds__(256) void scan_expand(const int* __restrict__ deg,
    const int* __restrict__ psum, int* __restrict__ rowptr, int N, int E)
{
    __shared__ int s[256];
    const int t = threadIdx.x;
    const int i = blockIdx.x * 256 + t;
    const int v = (i < N) ? deg[i] : 0;
    s[t] = v;
    __syncthreads();
    for (int off = 1; off < 256; off <<= 1) {
        const int u = (t >= off) ? s[t - off] : 0;
        __syncthreads();
        s[t] += u;
        __syncthreads();
    }
    if (i < N) rowptr[i] = psum[blockIdx.x] + s[t] - v;   // exclusive
    if (i == N - 1) rowptr[N] = E;
}

__global__ __launch_bounds__(256) void fill_kernel(const int* __restrict__ src,
    const int* __restrict__ dst, const int* __restrict__ rowptr,
    int* __restrict__ cursor, int* __restrict__ eidx, int E)
{
    const int e = blockIdx.x * 256 + threadIdx.x;
    if (e >= E) return;
    const int d = dst[e];
    const int p = atomicAdd(&cursor[d], 1);
    eidx[rowptr[d] + p] = src[e];
}

// ------- CSR gather from i16 features: full 64-lane, 4-edge ILP -------
template<int FD>
__global__ __launch_bounds__(256) void gather_kernel(
    const short* __restrict__ hq, const int* __restrict__ rowptr,
    const int* __restrict__ eidx, u16* __restrict__ aggb, int N)
{
    constexpr int GW = FD / 32;           // cols per lane: 6 (192) or 4 (128)
    constexpr int ND = GW / 2;            // dwords per load
    const int lane = threadIdx.x & 63;
    const int half = lane >> 5;
    const int g    = lane & 31;
    const int n    = blockIdx.x * 4 + (threadIdx.x >> 6);
    if (n >= N) return;
    const int beg = rowptr[n], end = rowptr[n + 1];

    int acc[GW];
#pragma unroll
    for (int i = 0; i < GW; ++i) acc[i] = 0;

    int j = beg + half;
    for (; j + 6 < end; j += 8) {         // 4 edges in flight per lane
        const int s0 = eidx[j],     s1 = eidx[j + 2];
        const int s2 = eidx[j + 4], s3 = eidx[j + 6];
        const unsigned int* p0 = (const unsigned int*)(hq + (size_t)s0 * FD + g * GW);
        const unsigned int* p1 = (const unsigned int*)(hq + (size_t)s1 * FD + g * GW);
        const unsigned int* p2 = (const unsigned int*)(hq + (size_t)s2 * FD + g * GW);
        const unsigned int* p3 = (const unsigned int*)(hq + (size_t)s3 * FD + g * GW);
        unsigned int u0[ND], u1[ND], u2[ND], u3[ND];
#pragma unroll
        for (int d = 0; d < ND; ++d) { u0[d] = p0[d]; u1[d] = p1[d]; u2[d] = p2[d]; u3[d] = p3[d]; }
#pragma unroll
        for (int d = 0; d < ND; ++d) {
            acc[2*d]   += (int)(short)(u0[d] & 0xffffu) + (int)(short)(u1[d] & 0xffffu)
                        + (int)(short)(u2[d] & 0xffffu) + (int)(short)(u3[d] & 0xffffu);
            acc[2*d+1] += (((int)u0[d]) >> 16) + (((int)u1[d]) >> 16)
                        + (((int)u2[d]) >> 16) + (((int)u3[d]) >> 16);
        }
    }
    for (; j < end; j += 2) {
        const int s0 = eidx[j];
        const unsigned int* p0 = (const unsigned int*)(hq + (size_t)s0 * FD + g * GW);
#pragma unroll
        for (int d = 0; d < ND; ++d) {
            const unsigned int u = p0[d];
            acc[2*d]   += (int)(short)(u & 0xffffu);
            acc[2*d+1] += ((int)u) >> 16;
        }
    }
#pragma unroll
    for (int i = 0; i < GW; ++i) acc[i] += __shfl_xor(acc[i], 32);

    if (half == 0) {
        unsigned int* q = (unsigned int*)(aggb + (size_t)n * FD + g * GW);
#pragma unroll
        for (int d = 0; d < ND; ++d) {
            const u16 lo = f2b((float)acc[2*d]   * QIS);
            const u16 hi = f2b((float)acc[2*d+1] * QIS);
            q[d] = (unsigned int)lo | ((unsigned int)hi << 16);
        }
    }
}

// -------- MFMA GEMM: 512 thr / 8 waves; block = 256 rows x 192 cols ----------
template<int K1, int K2>
__global__ __launch_bounds__(512, 1) void gemm_mfma(
    const u16* __restrict__ A1, const u16* __restrict__ A2,
    const u16* __restrict__ Wb, const float* __restrict__ bias,
    u16* __restrict__ Hout, long long* __restrict__ statsq, int N)
{
    constexpr int KC  = K1 + K2;
    constexpr int NC  = KC / 32;
    constexpr int NC1 = K1 / 32;
    __shared__ u16 bsh[HD * KC];          // 98KB (KC=256) / 147KB (KC=384)

    const int tid  = threadIdx.x;
    const int wave = tid >> 6, lane = tid & 63;
    const int c = lane & 15, kg = lane >> 4;
    const int row0 = blockIdx.x * 256 + wave * 32;

    {   // stage whole panel linearly (512 thr x 16B = 8KB per iter)
        constexpr int NST = (HD * KC) / (512 * 8);
        const u16* wsrc = Wb + tid * 8;
        u16* ldst = bsh + tid * 8;
#pragma unroll
        for (int i = 0; i < NST; ++i)
            async_cp16(wsrc + i * 4096, ldst + i * 4096);
    }

    int arc[2];
#pragma unroll
    for (int m = 0; m < 2; ++m) {
        const int r = row0 + m * 16 + c;
        arc[m] = r < N ? r : N - 1;
    }

    f32x4 acc[2][12];
#pragma unroll
    for (int m = 0; m < 2; ++m)
#pragma unroll
        for (int f = 0; f < 12; ++f) acc[m][f] = (f32x4){0.f, 0.f, 0.f, 0.f};

    __syncthreads();   // drains global_load_lds; only barrier before epilogue

    for (int ch = 0; ch < NC; ++ch) {
        const int kk = ch * 32;
        bf16x8 a[2];
#pragma unroll
        for (int m = 0; m < 2; ++m) {
            const u16* p = (ch < NC1) ? (A1 + (size_t)arc[m] * K1 + kk + kg * 8)
                                      : (A2 + (size_t)arc[m] * K2 + (kk - K1) + kg * 8);
            a[m] = *(const bf16x8*)p;
        }
#pragma unroll
        for (int f = 0; f < 12; ++f) {
            const bf16x8 b = *(const bf16x8*)&bsh[ch * 6144 + f * 512 + kg * 128 + c * 8];
            acc[0][f] = __builtin_amdgcn_mfma_f32_16x16x32_bf16(a[0], b, acc[0][f], 0, 0, 0);
            acc[1][f] = __builtin_amdgcn_mfma_f32_16x16x32_bf16(a[1], b, acc[1][f], 0, 0, 0);
        }
    }

    // ---- epilogue: bias + store + BN partial sums ----
    float s1v[12], s2v[12];
#pragma unroll
    for (int f = 0; f < 12; ++f) { s1v[f] = 0.f; s2v[f] = 0.f; }

#pragma unroll
    for (int f = 0; f < 12; ++f) {
        const int col = f * 16 + c;
        const float bv = bias[col];
#pragma unroll
        for (int m = 0; m < 2; ++m)
#pragma unroll
            for (int r = 0; r < 4; ++r) {
                const int orow = row0 + m * 16 + kg * 4 + r;
                if (orow < N) {
                    const float v = acc[m][f][r] + bv;
                    s1v[f] += v;
                    s2v[f] += v * v;
                    Hout[(size_t)orow * HD + col] = f2b(v);
                }
            }
    }
#pragma unroll
    for (int f = 0; f < 12; ++f) {
        s1v[f] += __shfl_xor(s1v[f], 16); s1v[f] += __shfl_xor(s1v[f], 32);
        s2v[f] += __shfl_xor(s2v[f], 16); s2v[f] += __shfl_xor(s2v[f], 32);
    }
    __syncthreads();                       // all waves done with bsh
    float* red = (float*)bsh;              // reuse panel LDS: 2 x 8 x 192 floats
    if (kg == 0) {
#pragma unroll
        for (int f = 0; f < 12; ++f) {
            red[wave * HD + f * 16 + c]            = s1v[f];
            red[8 * HD + wave * HD + f * 16 + c]   = s2v[f];
        }
    }
    __syncthreads();
    if (tid < HD) {
        float a1 = 0.f, a2 = 0.f;
#pragma unroll
        for (int w = 0; w < 8; ++w) {
            a1 += red[w * HD + tid];
            a2 += red[8 * HD + w * HD + tid];
        }
        atomicAdd((unsigned long long*)&statsq[tid],
                  (unsigned long long)(long long)llrintf(a1 * STAT_S));
        atomicAdd((unsigned long long*)&statsq[HD + tid],
                  (unsigned long long)(long long)llrintf(a2 * STAT_S));
    }
}

// ------- h = relu(hpre*scale + shift) -> bf16 + i16; BN params from statsq -----
__global__ __launch_bounds__(256) void norm_relu(const u16* __restrict__ hpre,
    u16* __restrict__ hb, short* __restrict__ hq,
    const long long* __restrict__ statsq,
    const float* __restrict__ gamma, const float* __restrict__ beta, int N)
{
    __shared__ float sc[HD], sh[HD];
    const int t = threadIdx.x;
    if (t < HD) {
        const float inv = 1.0f / (float)N;
        const float sum = (float)statsq[t] * STAT_IS;
        const float sq  = (float)statsq[HD + t] * STAT_IS;
        const float mu  = sum * inv;
        const float var = sq * inv - mu * mu;
        const float s   = gamma[t] * rsqrtf(var + BNEPS);
        sc[t] = s; sh[t] = beta[t] - mu * s;
    }
    __syncthreads();
    const int idx = blockIdx.x * 256 + t;
    const int total = N * (HD / 8);
    if (idx >= total) return;
    const int c8 = idx % (HD / 8);
    uint4 packed = ((const uint4*)hpre)[idx];
    const u16* pu = (const u16*)&packed;
    u16 ob[8]; short oq[8];
#pragma unroll
    for (int j = 0; j < 8; ++j) {
        const int cc = c8 * 8 + j;
        const float v = fmaxf(0.f, fmaf(b2f(pu[j]), sc[cc], sh[cc]));
        ob[j] = f2b(v);
        oq[j] = (short)__float2int_rn(fminf(v, 15.9f) * QS);
    }
    ((uint4*)hb)[idx] = *(uint4*)ob;
    ((uint4*)hq)[idx] = *(uint4*)oq;
}

// ------- parallel mean-pool partials: run-flush int32 fixed-point atomics -----
// 196 blocks x 192 thr = 8 row-threads x 24 col-octets; 256 rows per block.
__global__ __launch_bounds__(192) void pool_partial(const u16* __restrict__ hb,
    const int* __restrict__ batch, int* __restrict__ gsumq, int N)
{
    const int t   = threadIdx.x;
    const int rl  = t / 24;        // 0..7
    const int oct = t % 24;        // 0..23
    const int r0  = blockIdx.x * 256;
    const int rend = (r0 + 256 < N) ? r0 + 256 : N;

    float facc[8];
#pragma unroll
    for (int i = 0; i < 8; ++i) facc[i] = 0.f;
    int cur = -1;

    for (int r = r0 + rl; r < rend; r += 8) {
        const int b = batch[r];
        if (b != cur) {
            if (cur >= 0) {
                int* q = gsumq + (size_t)cur * HD + oct * 8;
#pragma unroll
                for (int i = 0; i < 8; ++i)
                    atomicAdd(&q[i], __float2int_rn(facc[i] * POOL_S));
            }
#pragma unroll
            for (int i = 0; i < 8; ++i) facc[i] = 0.f;
            cur = b;
        }
        const uint4 pv = *(const uint4*)(hb + (size_t)r * HD + oct * 8);
        const u16* pu = (const u16*)&pv;
#pragma unroll
        for (int i = 0; i < 8; ++i) facc[i] += b2f(pu[i]);
    }
    if (cur >= 0) {
        int* q = gsumq + (size_t)cur * HD + oct * 8;
#pragma unroll
        for (int i = 0; i < 8; ++i)
            atomicAdd(&q[i], __float2int_rn(facc[i] * POOL_S));
    }
}

// ------- MLP head: gv from fixed-point pool sums; coalesced weights -------
__global__ __launch_bounds__(192) void head_kernel(
    const int* __restrict__ gsumq, const int* __restrict__ batch, int N,
    const float* __restrict__ w1t, const float* __restrict__ b1,
    const float* __restrict__ w2t, const float* __restrict__ b2,
    const float* __restrict__ ow, const float* __restrict__ ob,
    float* __restrict__ out)
{
    __shared__ float gv[HD];
    __shared__ float h1[HD];
    __shared__ float h2[HD];
    const int g = blockIdx.x;
    const int t = threadIdx.x;

    int lo = 0, hi = N;
    while (lo < hi) { int m = (lo + hi) >> 1; if (batch[m] < g) lo = m + 1; else hi = m; }
    const int start = lo;
    hi = N;
    while (lo < hi) { int m = (lo + hi) >> 1; if (batch[m] < g + 1) lo = m + 1; else hi = m; }
    const int end = lo;
    const float cnt = fmaxf((float)(end - start), 1.0f);

    gv[t] = (float)gsumq[(size_t)g * HD + t] * POOL_IS / cnt;
    __syncthreads();
    {
        float acc = b1[t];
#pragma unroll 4
        for (int k = 0; k < HD; ++k)
            acc = fmaf(gv[k], w1t[k * HD + t], acc);
        h1[t] = fmaxf(acc, 0.f);
    }
    __syncthreads();
    {
        float acc = b2[t];
#pragma unroll 4
        for (int k = 0; k < HD; ++k)
            acc = fmaf(h1[k], w2t[k * HD + t], acc);
        h2[t] = acc * ow[t];
    }
    __syncthreads();
    if (t < 64) {
        float s = h2[t] + h2[t + 64] + h2[t + 128];
#pragma unroll
        for (int d = 1; d < 64; d <<= 1) s += __shfl_xor(s, d);
        if (t == 0) out[g] = s + ob[0];
    }
}

extern "C" void kernel_launch(void* const* d_in, const int* in_sizes, int n_in,
                              void* d_out, int out_size, void* d_ws, size_t ws_size,
                              hipStream_t stream)
{
    const float* x       = (const float*)d_in[0];
    const int*   ei      = (const int*)d_in[1];
    const int*   batch   = (const int*)d_in[2];
    const float* w_rel0  = (const float*)d_in[4];
    const float* b_rel0  = (const float*)d_in[5];
    const float* w_root0 = (const float*)d_in[6];
    const float* w_rel   = (const float*)d_in[7];
    const float* b_rel   = (const float*)d_in[8];
    const float* w_root  = (const float*)d_in[9];
    const float* bn_g    = (const float*)d_in[10];
    const float* bn_b    = (const float*)d_in[11];
    const float* hw1     = (const float*)d_in[12];
    const float* hb1     = (const float*)d_in[13];
    const float* hw2     = (const float*)d_in[14];
    const float* hb2     = (const float*)d_in[15];
    const float* ow      = (const float*)d_in[16];
    const float* ob      = (const float*)d_in[17];
    float* out = (float*)d_out;

    const int N = in_sizes[0] / FD0;
    const int E = in_sizes[1] / 2;
    const int* src = ei;
    const int* dst = ei + E;
    const int M = idiv(N, 256);

    char* ws = (char*)d_ws;
    size_t off = 0;
    u16*   xb   = (u16*)(ws + off);   off += (size_t)N * FD0 * 2;
    short* xq   = (short*)(ws + off); off += (size_t)N * FD0 * 2;
    u16*   hb   = (u16*)(ws + off);   off += (size_t)N * HD * 2;
    short* hq   = (short*)(ws + off); off += (size_t)N * HD * 2;
    u16*   aggb = (u16*)(ws + off);   off += (size_t)N * HD * 2;
    u16*   hpre = (u16*)(ws + off);   off += (size_t)N * HD * 2;
    u16*   wp0  = (u16*)(ws + off);   off += (size_t)HD * 2 * FD0 * 2;
    u16*   wp123= (u16*)(ws + off);   off += (size_t)3 * HD * 2 * HD * 2;
    off = (off + 15) & ~(size_t)15;
    float* w1t = (float*)(ws + off); off += (size_t)HD * HD * 4;
    float* w2t = (float*)(ws + off); off += (size_t)HD * HD * 4;
    long long* statsq4 = (long long*)(ws + off); off += 4 * 2 * HD * sizeof(long long);
    int*   gsumq  = (int*)(ws + off); off += (size_t)NG * HD * 4;   // adjacent to statsq4
    int*   rowptr = (int*)(ws + off); off += (size_t)(N + 1) * 4;
    int*   deg    = (int*)(ws + off); off += (size_t)N * 4;
    int*   psum   = (int*)(ws + off); off += (size_t)M * 4;
    int*   eidx   = (int*)(ws + off); off += (size_t)E * 4;

    const dim3 b256(256), b512(512), b192(192);

    // ---- conversions & CSR build & zeroing (one memset covers statsq4+gsumq)
    convert_x<<<idiv(N * FD0 / 4, 256), b256, 0, stream>>>(x, xb, xq, N * FD0 / 4);
    pack_all<<<idiv(HD * 2 * FD0 + 3 * HD * 2 * HD, 256), b256, 0, stream>>>(
        w_rel0, w_root0, w_rel, w_root, wp0, wp123);
    transpose_all<<<idiv(2 * HD * HD, 256), b256, 0, stream>>>(hw1, hw2, w1t, w2t);
    hipMemsetAsync(statsq4, 0, 4 * 2 * HD * sizeof(long long) + (size_t)NG * HD * 4,
                   stream);
    hipMemsetAsync(deg, 0, (size_t)N * sizeof(int), stream);
    hist_kernel<<<idiv(E, 256), b256, 0, stream>>>(dst, deg, E);
    scan_partial<<<M, b256, 0, stream>>>(deg, psum, N);
    scan_small<<<1, b256, 0, stream>>>(psum, M);
    scan_expand<<<M, b256, 0, stream>>>(deg, psum, rowptr, N, E);
    hipMemsetAsync(deg, 0, (size_t)N * sizeof(int), stream);
    fill_kernel<<<idiv(E, 256), b256, 0, stream>>>(src, dst, rowptr, deg, eidx, E);

    // ---- layer 0 (K=128+128)
    gather_kernel<FD0><<<idiv(N, 4), b256, 0, stream>>>(xq, rowptr, eidx, aggb, N);
    gemm_mfma<FD0, FD0><<<idiv(N, 256), b512, 0, stream>>>(aggb, xb, wp0, b_rel0,
                                                           hpre, statsq4, N);
    norm_relu<<<idiv(N * (HD / 8), 256), b256, 0, stream>>>(hpre, hb, hq, statsq4,
                                                            bn_g, bn_b, N);

    // ---- layers 1..3 (K=192+192)
    for (int i = 0; i < 3; ++i) {
        long long* statsq = statsq4 + (size_t)(i + 1) * 2 * HD;
        gather_kernel<HD><<<idiv(N, 4), b256, 0, stream>>>(hq, rowptr, eidx, aggb, N);
        gemm_mfma<HD, HD><<<idiv(N, 256), b512, 0, stream>>>(
            aggb, hb, wp123 + (size_t)i * HD * 2 * HD,
            b_rel + (size_t)i * HD, hpre, statsq, N);
        norm_relu<<<idiv(N * (HD / 8), 256), b256, 0, stream>>>(hpre, hb, hq, statsq,
            bn_g + (size_t)(i + 1) * HD, bn_b + (size_t)(i + 1) * HD, N);
    }

    // ---- parallel pool partials + tiny head
    pool_partial<<<idiv(N, 256), b192, 0, stream>>>(hb, batch, gsumq, N);
    head_kernel<<<NG, b192, 0, stream>>>(gsumq, batch, N, w1t, hb1, w2t, hb2,
                                         ow, ob, out);
}

// Round 13
// 405.803 us; speedup vs baseline: 1.0316x; 1.0316x over previous
//
#include <hip/hip_runtime.h>

#define HD 192
#define FD0 128
#define NG 256
#define BNEPS 1e-5f

#define STAT_S  1048576.0f        // 2^20 fixed-point scale for BN stats
#define STAT_IS (1.0f / 1048576.0f)
#define POOL_S  65536.0f          // 2^16 fixed-point scale for pooling
#define POOL_IS (1.0f / 65536.0f)

typedef unsigned short u16;
typedef __attribute__((ext_vector_type(8))) short bf16x8;
typedef __attribute__((ext_vector_type(4))) float f32x4;

static inline int idiv(int a, int b) { return (a + b - 1) / b; }

__device__ __forceinline__ float b2f(u16 u) {
    unsigned int v = ((unsigned int)u) << 16;
    return __builtin_bit_cast(float, v);
}
__device__ __forceinline__ float b2f_lo(unsigned int u) {
    return __builtin_bit_cast(float, u << 16);
}
__device__ __forceinline__ float b2f_hi(unsigned int u) {
    return __builtin_bit_cast(float, u & 0xffff0000u);
}
__device__ __forceinline__ u16 f2b(float f) {
    unsigned int x = __builtin_bit_cast(unsigned int, f);
    return (u16)((x + 0x7FFFu + ((x >> 16) & 1u)) >> 16);   // RNE
}

// async global->LDS, 16B per lane; LDS dest = uniform base + lane*16
__device__ __forceinline__ void async_cp16(const void* g, void* l) {
    __builtin_amdgcn_global_load_lds(
        (const __attribute__((address_space(1))) unsigned int*)g,
        (__attribute__((address_space(3))) unsigned int*)l, 16, 0, 0);
}

// ---------------- x fp32 -> bf16 ----------------
__global__ __launch_bounds__(256) void convert_bf16(const float* __restrict__ in,
                                                    u16* __restrict__ out, int n4)
{
    const int i = blockIdx.x * 256 + threadIdx.x;
    if (i >= n4) return;
    const float4 v = ((const float4*)in)[i];
    u16 o[4] = { f2b(v.x), f2b(v.y), f2b(v.z), f2b(v.w) };
    ((ushort4*)out)[i] = *(ushort4*)o;
}

// ------- pack [Wr | Wt] bf16, MFMA-frag chunk order: [chunk][f12][kg][c][j] ---
__device__ __forceinline__ void pack_one(const float* __restrict__ wr,
    const float* __restrict__ wt, u16* __restrict__ out, int K, int idx)
{
    const int j  = idx & 7;
    const int t  = idx >> 3;
    const int c  = t & 15;
    const int kg = (t >> 4) & 3;
    const int rest = t >> 6;
    const int fglob = rest % 12;
    const int chunk = rest / 12;
    const int col = fglob * 16 + c;
    const int k   = chunk * 32 + kg * 8 + j;
    const float v = (k < K) ? wr[(size_t)col * K + k] : wt[(size_t)col * K + (k - K)];
    out[idx] = f2b(v);
}

// all weight packs + head transposes in ONE launch
__global__ __launch_bounds__(256) void pack_fuse(const float* __restrict__ wr0,
    const float* __restrict__ wt0, const float* __restrict__ w_rel,
    const float* __restrict__ w_root, const float* __restrict__ hw1,
    const float* __restrict__ hw2, u16* __restrict__ wp0,
    u16* __restrict__ wp123, float* __restrict__ w1t, float* __restrict__ w2t)
{
    const int T0 = HD * 2 * FD0;     // 49152
    const int T1 = HD * 2 * HD;      // 73728
    const int TW = HD * HD;          // 36864
    int idx = blockIdx.x * 256 + threadIdx.x;
    if (idx < T0) { pack_one(wr0, wt0, wp0, FD0, idx); return; }
    idx -= T0;
    if (idx < 3 * T1) {
        const int li = idx / T1;
        const int r  = idx - li * T1;
        pack_one(w_rel + (size_t)li * HD * HD, w_root + (size_t)li * HD * HD,
                 wp123 + (size_t)li * T1, HD, r);
        return;
    }
    idx -= 3 * T1;
    if (idx >= 2 * TW) return;
    const float* w = (idx < TW) ? hw1 : hw2;
    float*       o = (idx < TW) ? w1t : w2t;
    const int r = (idx < TW) ? idx : idx - TW;
    const int t = r % HD, k = r / HD;
    o[r] = w[(size_t)t * HD + k];
}

// ---------------- CSR build ----------------
__global__ __launch_bounds__(256) void hist_kernel(const int* __restrict__ dst,
                                                   int* __restrict__ deg, int E)
{
    const int e = blockIdx.x * 256 + threadIdx.x;
    if (e < E) atomicAdd(&deg[dst[e]], 1);
}

__global__ __launch_bounds__(256) void scan_partial(const int* __restrict__ deg,
                                                    int* __restrict__ psum, int N)
{
    __shared__ int s[256];
    const int t = threadIdx.x;
    const int i = blockIdx.x * 256 + t;
    s[t] = (i < N) ? deg[i] : 0;
    __syncthreads();
    for (int off = 128; off > 0; off >>= 1) {
        if (t < off) s[t] += s[t + off];
        __syncthreads();
    }
    if (t == 0) psum[blockIdx.x] = s[0];
}

__global__ __launch_bounds__(256) void scan_small(int* __restrict__ psum, int M)
{
    __shared__ int s[256];
    const int t = threadIdx.x;
    s[t] = (t < M) ? psum[t] : 0;
    __syncthreads();
    for (int off = 1; off < 256; off <<= 1) {
        const int u = (t >= off) ? s[t - off] : 0;
        __syncthreads();
        s[t] += u;
        __syncthreads();
    }
    if (t < M) psum[t] = (t == 0) ? 0 : s[t - 1];
}

// writes rowptr AND re-writes deg as the fill cursor (absolute base)
__global__ __launch_bounds__(256) void scan_expand(int* __restrict__ deg,
    const int* __restrict__ psum, int* __restrict__ rowptr, int N, int E)
{
    __shared__ int s[256];
    const int t = threadIdx.x;
    const int i = blockIdx.x * 256 + t;
    const int v = (i < N) ? deg[i] : 0;
    s[t] = v;
    __syncthreads();
    for (int off = 1; off < 256; off <<= 1) {
        const int u = (t >= off) ? s[t - off] : 0;
        __syncthreads();
        s[t] += u;
        __syncthreads();
    }
    if (i < N) {
        const int base = psum[blockIdx.x] + s[t] - v;   // exclusive
        rowptr[i] = base;
        deg[i]    = base;                                // cursor
    }
    if (i == N - 1) rowptr[N] = E;
}

__global__ __launch_bounds__(256) void fill_kernel(const int* __restrict__ src,
    const int* __restrict__ dst, int* __restrict__ cursor,
    int* __restrict__ eidx, int E)
{
    const int e = blockIdx.x * 256 + threadIdx.x;
    if (e >= E) return;
    const int p = atomicAdd(&cursor[dst[e]], 1);
    eidx[p] = src[e];
}

// ------- CSR gather (bf16 in, fp32 acc — fixed order => deterministic) -------
// wave per node; lane = (half, colgroup): 32 groups x GW shorts; 4-edge ILP.
template<int FD>
__global__ __launch_bounds__(256) void gather_kernel(
    const u16* __restrict__ hb, const int* __restrict__ rowptr,
    const int* __restrict__ eidx, u16* __restrict__ aggb, int N)
{
    constexpr int GW = FD / 32;           // shorts per lane: 6 (192) or 4 (128)
    constexpr int ND = GW / 2;            // dwords per load
    const int lane = threadIdx.x & 63;
    const int half = lane >> 5;
    const int g    = lane & 31;
    const int n    = blockIdx.x * 4 + (threadIdx.x >> 6);
    if (n >= N) return;
    const int beg = rowptr[n], end = rowptr[n + 1];

    float acc[GW];
#pragma unroll
    for (int i = 0; i < GW; ++i) acc[i] = 0.f;

    int j = beg + half;
    for (; j + 6 < end; j += 8) {         // 4 edges in flight per lane
        const int s0 = eidx[j],     s1 = eidx[j + 2];
        const int s2 = eidx[j + 4], s3 = eidx[j + 6];
        const unsigned int* p0 = (const unsigned int*)(hb + (size_t)s0 * FD + g * GW);
        const unsigned int* p1 = (const unsigned int*)(hb + (size_t)s1 * FD + g * GW);
        const unsigned int* p2 = (const unsigned int*)(hb + (size_t)s2 * FD + g * GW);
        const unsigned int* p3 = (const unsigned int*)(hb + (size_t)s3 * FD + g * GW);
        unsigned int u0[ND], u1[ND], u2[ND], u3[ND];
#pragma unroll
        for (int d = 0; d < ND; ++d) { u0[d] = p0[d]; u1[d] = p1[d]; u2[d] = p2[d]; u3[d] = p3[d]; }
#pragma unroll
        for (int d = 0; d < ND; ++d) {
            acc[2*d]   += b2f_lo(u0[d]) + b2f_lo(u1[d]) + b2f_lo(u2[d]) + b2f_lo(u3[d]);
            acc[2*d+1] += b2f_hi(u0[d]) + b2f_hi(u1[d]) + b2f_hi(u2[d]) + b2f_hi(u3[d]);
        }
    }
    for (; j < end; j += 2) {
        const int s0 = eidx[j];
        const unsigned int* p0 = (const unsigned int*)(hb + (size_t)s0 * FD + g * GW);
#pragma unroll
        for (int d = 0; d < ND; ++d) {
            const unsigned int u = p0[d];
            acc[2*d]   += b2f_lo(u);
            acc[2*d+1] += b2f_hi(u);
        }
    }
#pragma unroll
    for (int i = 0; i < GW; ++i) acc[i] += __shfl_xor(acc[i], 32);

    if (half == 0) {
        unsigned int* q = (unsigned int*)(aggb + (size_t)n * FD + g * GW);
#pragma unroll
        for (int d = 0; d < ND; ++d) {
            const u16 lo = f2b(acc[2*d]);
            const u16 hi = f2b(acc[2*d+1]);
            q[d] = (unsigned int)lo | ((unsigned int)hi << 16);
        }
    }
}

// -------- MFMA GEMM: 512 thr / 8 waves; block = 256 rows x 192 cols ----------
// Full B panel resident in LDS (staged once, global_load_lds); K-loop fully
// unrolled with one-chunk-ahead A register prefetch; no barriers in loop.
template<int K1, int K2>
__global__ __launch_bounds__(512, 1) void gemm_mfma(
    const u16* __restrict__ A1, const u16* __restrict__ A2,
    const u16* __restrict__ Wb, const float* __restrict__ bias,
    u16* __restrict__ Hout, long long* __restrict__ statsq, int N)
{
    constexpr int KC  = K1 + K2;
    constexpr int NC  = KC / 32;
    constexpr int NC1 = K1 / 32;
    __shared__ u16 bsh[HD * KC];          // 98KB (KC=256) / 147KB (KC=384)

    const int tid  = threadIdx.x;
    const int wave = tid >> 6, lane = tid & 63;
    const int c = lane & 15, kg = lane >> 4;
    const int row0 = blockIdx.x * 256 + wave * 32;

    {   // stage whole panel linearly (512 thr x 16B = 8KB per iter)
        constexpr int NST = (HD * KC) / (512 * 8);
        const u16* wsrc = Wb + tid * 8;
        u16* ldst = bsh + tid * 8;
#pragma unroll
        for (int i = 0; i < NST; ++i)
            async_cp16(wsrc + i * 4096, ldst + i * 4096);
    }

    int arc[2];
#pragma unroll
    for (int m = 0; m < 2; ++m) {
        const int r = row0 + m * 16 + c;
        arc[m] = r < N ? r : N - 1;
    }

    f32x4 acc[2][12];
#pragma unroll
    for (int m = 0; m < 2; ++m)
#pragma unroll
        for (int f = 0; f < 12; ++f) acc[m][f] = (f32x4){0.f, 0.f, 0.f, 0.f};

    auto aload = [&](int ch, bf16x8* d) {
#pragma unroll
        for (int m = 0; m < 2; ++m) {
            const u16* p = (ch < NC1)
                ? (A1 + (size_t)arc[m] * K1 + ch * 32 + kg * 8)
                : (A2 + (size_t)arc[m] * K2 + (ch - NC1) * 32 + kg * 8);
            d[m] = *(const bf16x8*)p;
        }
    };

    bf16x8 a_cur[2], a_nxt[2];
    aload(0, a_cur);      // in flight across the staging barrier
    __syncthreads();      // drains global_load_lds (and our A-load)

#pragma unroll
    for (int ch = 0; ch < NC; ++ch) {
        if (ch + 1 < NC) aload(ch + 1, a_nxt);   // prefetch next chunk's A
#pragma unroll
        for (int f = 0; f < 12; ++f) {
            const bf16x8 b = *(const bf16x8*)&bsh[ch * 6144 + f * 512 + kg * 128 + c * 8];
            acc[0][f] = __builtin_amdgcn_mfma_f32_16x16x32_bf16(a_cur[0], b, acc[0][f], 0, 0, 0);
            acc[1][f] = __builtin_amdgcn_mfma_f32_16x16x32_bf16(a_cur[1], b, acc[1][f], 0, 0, 0);
        }
        a_cur[0] = a_nxt[0]; a_cur[1] = a_nxt[1];
    }

    // ---- epilogue: bias + store + BN partial sums ----
    float s1v[12], s2v[12];
#pragma unroll
    for (int f = 0; f < 12; ++f) { s1v[f] = 0.f; s2v[f] = 0.f; }

#pragma unroll
    for (int f = 0; f < 12; ++f) {
        const int col = f * 16 + c;
        const float bv = bias[col];
#pragma unroll
        for (int m = 0; m < 2; ++m)
#pragma unroll
            for (int r = 0; r < 4; ++r) {
                const int orow = row0 + m * 16 + kg * 4 + r;
                if (orow < N) {
                    const float v = acc[m][f][r] + bv;
                    s1v[f] += v;
                    s2v[f] += v * v;
                    Hout[(size_t)orow * HD + col] = f2b(v);
                }
            }
    }
#pragma unroll
    for (int f = 0; f < 12; ++f) {
        s1v[f] += __shfl_xor(s1v[f], 16); s1v[f] += __shfl_xor(s1v[f], 32);
        s2v[f] += __shfl_xor(s2v[f], 16); s2v[f] += __shfl_xor(s2v[f], 32);
    }
    __syncthreads();                       // all waves done with bsh
    float* red = (float*)bsh;              // reuse panel LDS: 2 x 8 x 192 floats
    if (kg == 0) {
#pragma unroll
        for (int f = 0; f < 12; ++f) {
            red[wave * HD + f * 16 + c]            = s1v[f];
            red[8 * HD + wave * HD + f * 16 + c]   = s2v[f];
        }
    }
    __syncthreads();
    if (tid < HD) {
        float a1 = 0.f, a2 = 0.f;
#pragma unroll
        for (int w = 0; w < 8; ++w) {
            a1 += red[w * HD + tid];
            a2 += red[8 * HD + w * HD + tid];
        }
        atomicAdd((unsigned long long*)&statsq[tid],
                  (unsigned long long)(long long)llrintf(a1 * STAT_S));
        atomicAdd((unsigned long long*)&statsq[HD + tid],
                  (unsigned long long)(long long)llrintf(a2 * STAT_S));
    }
}

// ------- h = relu(hpre*scale + shift) -> bf16; BN params from statsq -----
__global__ __launch_bounds__(256) void norm_relu(const u16* __restrict__ hpre,
    u16* __restrict__ hb, const long long* __restrict__ statsq,
    const float* __restrict__ gamma, const float* __restrict__ beta, int N)
{
    __shared__ float sc[HD], sh[HD];
    const int t = threadIdx.x;
    if (t < HD) {
        const float inv = 1.0f / (float)N;
        const float sum = (float)statsq[t] * STAT_IS;
        const float sq  = (float)statsq[HD + t] * STAT_IS;
        const float mu  = sum * inv;
        const float var = sq * inv - mu * mu;
        const float s   = gamma[t] * rsqrtf(var + BNEPS);
        sc[t] = s; sh[t] = beta[t] - mu * s;
    }
    __syncthreads();
    const int idx = blockIdx.x * 256 + t;
    const int total = N * (HD / 8);
    if (idx >= total) return;
    const int c8 = idx % (HD / 8);
    uint4 packed = ((const uint4*)hpre)[idx];
    const u16* pu = (const u16*)&packed;
    u16 ob[8];
#pragma unroll
    for (int j = 0; j < 8; ++j) {
        const int cc = c8 * 8 + j;
        ob[j] = f2b(fmaxf(0.f, fmaf(b2f(pu[j]), sc[cc], sh[cc])));
    }
    ((uint4*)hb)[idx] = *(uint4*)ob;
}

// ------- parallel mean-pool partials: run-flush int32 fixed-point atomics -----
__global__ __launch_bounds__(192) void pool_partial(const u16* __restrict__ hb,
    const int* __restrict__ batch, int* __restrict__ gsumq, int N)
{
    const int t   = threadIdx.x;
    const int rl  = t / 24;        // 0..7
    const int oct = t % 24;        // 0..23
    const int r0  = blockIdx.x * 256;
    const int rend = (r0 + 256 < N) ? r0 + 256 : N;

    float facc[8];
#pragma unroll
    for (int i = 0; i < 8; ++i) facc[i] = 0.f;
    int cur = -1;

    for (int r = r0 + rl; r < rend; r += 8) {
        const int b = batch[r];
        if (b != cur) {
            if (cur >= 0) {
                int* q = gsumq + (size_t)cur * HD + oct * 8;
#pragma unroll
                for (int i = 0; i < 8; ++i)
                    atomicAdd(&q[i], __float2int_rn(facc[i] * POOL_S));
            }
#pragma unroll
            for (int i = 0; i < 8; ++i) facc[i] = 0.f;
            cur = b;
        }
        const uint4 pv = *(const uint4*)(hb + (size_t)r * HD + oct * 8);
        const u16* pu = (const u16*)&pv;
#pragma unroll
        for (int i = 0; i < 8; ++i) facc[i] += b2f(pu[i]);
    }
    if (cur >= 0) {
        int* q = gsumq + (size_t)cur * HD + oct * 8;
#pragma unroll
        for (int i = 0; i < 8; ++i)
            atomicAdd(&q[i], __float2int_rn(facc[i] * POOL_S));
    }
}

// ------- MLP head: gv from fixed-point pool sums; coalesced weights -------
__global__ __launch_bounds__(192) void head_kernel(
    const int* __restrict__ gsumq, const int* __restrict__ batch, int N,
    const float* __restrict__ w1t, const float* __restrict__ b1,
    const float* __restrict__ w2t, const float* __restrict__ b2,
    const float* __restrict__ ow, const float* __restrict__ ob,
    float* __restrict__ out)
{
    __shared__ float gv[HD];
    __shared__ float h1[HD];
    __shared__ float h2[HD];
    const int g = blockIdx.x;
    const int t = threadIdx.x;

    int lo = 0, hi = N;
    while (lo < hi) { int m = (lo + hi) >> 1; if (batch[m] < g) lo = m + 1; else hi = m; }
    const int start = lo;
    hi = N;
    while (lo < hi) { int m = (lo + hi) >> 1; if (batch[m] < g + 1) lo = m + 1; else hi = m; }
    const int end = lo;
    const float cnt = fmaxf((float)(end - start), 1.0f);

    gv[t] = (float)gsumq[(size_t)g * HD + t] * POOL_IS / cnt;
    __syncthreads();
    {
        float acc = b1[t];
#pragma unroll 4
        for (int k = 0; k < HD; ++k)
            acc = fmaf(gv[k], w1t[k * HD + t], acc);
        h1[t] = fmaxf(acc, 0.f);
    }
    __syncthreads();
    {
        float acc = b2[t];
#pragma unroll 4
        for (int k = 0; k < HD; ++k)
            acc = fmaf(h1[k], w2t[k * HD + t], acc);
        h2[t] = acc * ow[t];
    }
    __syncthreads();
    if (t < 64) {
        float s = h2[t] + h2[t + 64] + h2[t + 128];
#pragma unroll
        for (int d = 1; d < 64; d <<= 1) s += __shfl_xor(s, d);
        if (t == 0) out[g] = s + ob[0];
    }
}

extern "C" void kernel_launch(void* const* d_in, const int* in_sizes, int n_in,
                              void* d_out, int out_size, void* d_ws, size_t ws_size,
                              hipStream_t stream)
{
    const float* x       = (const float*)d_in[0];
    const int*   ei      = (const int*)d_in[1];
    const int*   batch   = (const int*)d_in[2];
    const float* w_rel0  = (const float*)d_in[4];
    const float* b_rel0  = (const float*)d_in[5];
    const float* w_root0 = (const float*)d_in[6];
    const float* w_rel   = (const float*)d_in[7];
    const float* b_rel   = (const float*)d_in[8];
    const float* w_root  = (const float*)d_in[9];
    const float* bn_g    = (const float*)d_in[10];
    const float* bn_b    = (const float*)d_in[11];
    const float* hw1     = (const float*)d_in[12];
    const float* hb1     = (const float*)d_in[13];
    const float* hw2     = (const float*)d_in[14];
    const float* hb2     = (const float*)d_in[15];
    const float* ow      = (const float*)d_in[16];
    const float* ob      = (const float*)d_in[17];
    float* out = (float*)d_out;

    const int N = in_sizes[0] / FD0;
    const int E = in_sizes[1] / 2;
    const int* src = ei;
    const int* dst = ei + E;
    const int M = idiv(N, 256);

    char* ws = (char*)d_ws;
    size_t off = 0;
    u16*   xb   = (u16*)(ws + off);   off += (size_t)N * FD0 * 2;
    u16*   hb   = (u16*)(ws + off);   off += (size_t)N * HD * 2;
    u16*   aggb = (u16*)(ws + off);   off += (size_t)N * HD * 2;
    u16*   hpre = (u16*)(ws + off);   off += (size_t)N * HD * 2;
    u16*   wp0  = (u16*)(ws + off);   off += (size_t)HD * 2 * FD0 * 2;
    u16*   wp123= (u16*)(ws + off);   off += (size_t)3 * HD * 2 * HD * 2;
    off = (off + 15) & ~(size_t)15;
    float* w1t = (float*)(ws + off); off += (size_t)HD * HD * 4;
    float* w2t = (float*)(ws + off); off += (size_t)HD * HD * 4;
    long long* statsq4 = (long long*)(ws + off); off += 4 * 2 * HD * sizeof(long long);
    int*   gsumq  = (int*)(ws + off); off += (size_t)NG * HD * 4;   // adjacent to statsq4
    int*   rowptr = (int*)(ws + off); off += (size_t)(N + 1) * 4;
    int*   deg    = (int*)(ws + off); off += (size_t)N * 4;
    int*   psum   = (int*)(ws + off); off += (size_t)M * 4;
    int*   eidx   = (int*)(ws + off); off += (size_t)E * 4;

    const dim3 b256(256), b512(512), b192(192);

    // ---- prep: convert, pack+transpose, zero stats+gsum, CSR build
    convert_bf16<<<idiv(N * FD0 / 4, 256), b256, 0, stream>>>(x, xb, N * FD0 / 4);
    pack_fuse<<<idiv(HD * 2 * FD0 + 3 * HD * 2 * HD + 2 * HD * HD, 256), b256, 0,
                stream>>>(w_rel0, w_root0, w_rel, w_root, hw1, hw2,
                          wp0, wp123, w1t, w2t);
    hipMemsetAsync(statsq4, 0, 4 * 2 * HD * sizeof(long long) + (size_t)NG * HD * 4,
                   stream);
    hipMemsetAsync(deg, 0, (size_t)N * sizeof(int), stream);
    hist_kernel<<<idiv(E, 256), b256, 0, stream>>>(dst, deg, E);
    scan_partial<<<M, b256, 0, stream>>>(deg, psum, N);
    scan_small<<<1, b256, 0, stream>>>(psum, M);
    scan_expand<<<M, b256, 0, stream>>>(deg, psum, rowptr, N, E);  // deg -> cursor
    fill_kernel<<<idiv(E, 256), b256, 0, stream>>>(src, dst, deg, eidx, E);

    // ---- layer 0 (K=128+128)
    gather_kernel<FD0><<<idiv(N, 4), b256, 0, stream>>>(xb, rowptr, eidx, aggb, N);
    gemm_mfma<FD0, FD0><<<idiv(N, 256), b512, 0, stream>>>(aggb, xb, wp0, b_rel0,
                                                           hpre, statsq4, N);
    norm_relu<<<idiv(N * (HD / 8), 256), b256, 0, stream>>>(hpre, hb, statsq4,
                                                            bn_g, bn_b, N);

    // ---- layers 1..3 (K=192+192)
    for (int i = 0; i < 3; ++i) {
        long long* statsq = statsq4 + (size_t)(i + 1) * 2 * HD;
        gather_kernel<HD><<<idiv(N, 4), b256, 0, stream>>>(hb, rowptr, eidx, aggb, N);
        gemm_mfma<HD, HD><<<idiv(N, 256), b512, 0, stream>>>(
            aggb, hb, wp123 + (size_t)i * HD * 2 * HD,
            b_rel + (size_t)i * HD, hpre, statsq, N);
        norm_relu<<<idiv(N * (HD / 8), 256), b256, 0, stream>>>(hpre, hb, statsq,
            bn_g + (size_t)(i + 1) * HD, bn_b + (size_t)(i + 1) * HD, N);
    }

    // ---- parallel pool partials + tiny head
    pool_partial<<<idiv(N, 256), b192, 0, stream>>>(hb, batch, gsumq, N);
    head_kernel<<<NG, b192, 0, stream>>>(gsumq, batch, N, w1t, hb1, w2t, hb2,
                                         ow, ob, out);
}

// Round 14
// 391.450 us; speedup vs baseline: 1.0695x; 1.0367x over previous
//
#include <hip/hip_runtime.h>

#define HD 192
#define FD0 128
#define NG 256
#define BNEPS 1e-5f

#define STAT_S  1048576.0f        // 2^20 fixed-point scale for BN stats
#define STAT_IS (1.0f / 1048576.0f)
#define POOL_S  65536.0f          // 2^16 fixed-point scale for pooling
#define POOL_IS (1.0f / 65536.0f)

typedef unsigned short u16;
typedef __attribute__((ext_vector_type(8))) short bf16x8;
typedef __attribute__((ext_vector_type(4))) float f32x4;

static inline int idiv(int a, int b) { return (a + b - 1) / b; }

__device__ __forceinline__ float b2f(u16 u) {
    unsigned int v = ((unsigned int)u) << 16;
    return __builtin_bit_cast(float, v);
}
__device__ __forceinline__ u16 f2b(float f) {
    unsigned int x = __builtin_bit_cast(unsigned int, f);
    return (u16)((x + 0x7FFFu + ((x >> 16) & 1u)) >> 16);   // RNE
}

// BN scale/shift from fixed-point sum/sumsq (statsq layout: [HD sum][HD sumsq])
__device__ __forceinline__ void bn_params(const long long* __restrict__ statsq,
    const float* __restrict__ gamma, const float* __restrict__ beta,
    int N, int c, float& sc, float& sh)
{
    const float inv = 1.0f / (float)N;
    const float sum = (float)statsq[c] * STAT_IS;
    const float sq  = (float)statsq[HD + c] * STAT_IS;
    const float mu  = sum * inv;
    const float var = sq * inv - mu * mu;
    const float s   = gamma[c] * rsqrtf(var + BNEPS);
    sc = s; sh = beta[c] - mu * s;
}

// async global->LDS, 16B per lane; LDS dest = uniform base + lane*16
__device__ __forceinline__ void async_cp16(const void* g, void* l) {
    __builtin_amdgcn_global_load_lds(
        (const __attribute__((address_space(1))) unsigned int*)g,
        (__attribute__((address_space(3))) unsigned int*)l, 16, 0, 0);
}

// ---------------- x fp32 -> bf16 ----------------
__global__ __launch_bounds__(256) void convert_bf16(const float* __restrict__ in,
                                                    u16* __restrict__ out, int n4)
{
    const int i = blockIdx.x * 256 + threadIdx.x;
    if (i >= n4) return;
    const float4 v = ((const float4*)in)[i];
    u16 o[4] = { f2b(v.x), f2b(v.y), f2b(v.z), f2b(v.w) };
    ((ushort4*)out)[i] = *(ushort4*)o;
}

// ------- pack [Wr | Wt] bf16, MFMA-frag chunk order: [chunk][f12][kg][c][j] ---
__device__ __forceinline__ void pack_one(const float* __restrict__ wr,
    const float* __restrict__ wt, u16* __restrict__ out, int K, int idx)
{
    const int j  = idx & 7;
    const int t  = idx >> 3;
    const int c  = t & 15;
    const int kg = (t >> 4) & 3;
    const int rest = t >> 6;
    const int fglob = rest % 12;
    const int chunk = rest / 12;
    const int col = fglob * 16 + c;
    const int k   = chunk * 32 + kg * 8 + j;
    const float v = (k < K) ? wr[(size_t)col * K + k] : wt[(size_t)col * K + (k - K)];
    out[idx] = f2b(v);
}

// all weight packs + head transposes in ONE launch
__global__ __launch_bounds__(256) void pack_fuse(const float* __restrict__ wr0,
    const float* __restrict__ wt0, const float* __restrict__ w_rel,
    const float* __restrict__ w_root, const float* __restrict__ hw1,
    const float* __restrict__ hw2, u16* __restrict__ wp0,
    u16* __restrict__ wp123, float* __restrict__ w1t, float* __restrict__ w2t)
{
    const int T0 = HD * 2 * FD0;     // 49152
    const int T1 = HD * 2 * HD;      // 73728
    const int TW = HD * HD;          // 36864
    int idx = blockIdx.x * 256 + threadIdx.x;
    if (idx < T0) { pack_one(wr0, wt0, wp0, FD0, idx); return; }
    idx -= T0;
    if (idx < 3 * T1) {
        const int li = idx / T1;
        const int r  = idx - li * T1;
        pack_one(w_rel + (size_t)li * HD * HD, w_root + (size_t)li * HD * HD,
                 wp123 + (size_t)li * T1, HD, r);
        return;
    }
    idx -= 3 * T1;
    if (idx >= 2 * TW) return;
    const float* w = (idx < TW) ? hw1 : hw2;
    float*       o = (idx < TW) ? w1t : w2t;
    const int r = (idx < TW) ? idx : idx - TW;
    const int t = r % HD, k = r / HD;
    o[r] = w[(size_t)t * HD + k];
}

// ---------------- CSR build ----------------
__global__ __launch_bounds__(256) void hist_kernel(const int* __restrict__ dst,
                                                   int* __restrict__ deg, int E)
{
    const int e = blockIdx.x * 256 + threadIdx.x;
    if (e < E) atomicAdd(&deg[dst[e]], 1);
}

__global__ __launch_bounds__(256) void scan_partial(const int* __restrict__ deg,
                                                    int* __restrict__ psum, int N)
{
    __shared__ int s[256];
    const int t = threadIdx.x;
    const int i = blockIdx.x * 256 + t;
    s[t] = (i < N) ? deg[i] : 0;
    __syncthreads();
    for (int off = 128; off > 0; off >>= 1) {
        if (t < off) s[t] += s[t + off];
        __syncthreads();
    }
    if (t == 0) psum[blockIdx.x] = s[0];
}

__global__ __launch_bounds__(256) void scan_small(int* __restrict__ psum, int M)
{
    __shared__ int s[256];
    const int t = threadIdx.x;
    s[t] = (t < M) ? psum[t] : 0;
    __syncthreads();
    for (int off = 1; off < 256; off <<= 1) {
        const int u = (t >= off) ? s[t - off] : 0;
        __syncthreads();
        s[t] += u;
        __syncthreads();
    }
    if (t < M) psum[t] = (t == 0) ? 0 : s[t - 1];
}

// writes rowptr AND re-writes deg as the fill cursor (absolute base)
__global__ __launch_bounds__(256) void scan_expand(int* __restrict__ deg,
    const int* __restrict__ psum, int* __restrict__ rowptr, int N, int E)
{
    __shared__ int s[256];
    const int t = threadIdx.x;
    const int i = blockIdx.x * 256 + t;
    const int v = (i < N) ? deg[i] : 0;
    s[t] = v;
    __syncthreads();
    for (int off = 1; off < 256; off <<= 1) {
        const int u = (t >= off) ? s[t - off] : 0;
        __syncthreads();
        s[t] += u;
        __syncthreads();
    }
    if (i < N) {
        const int base = psum[blockIdx.x] + s[t] - v;   // exclusive
        rowptr[i] = base;
        deg[i]    = base;                                // cursor
    }
    if (i == N - 1) rowptr[N] = E;
}

__global__ __launch_bounds__(256) void fill_kernel(const int* __restrict__ src,
    const int* __restrict__ dst, int* __restrict__ cursor,
    int* __restrict__ eidx, int E)
{
    const int e = blockIdx.x * 256 + threadIdx.x;
    if (e >= E) return;
    const int p = atomicAdd(&cursor[dst[e]], 1);
    eidx[p] = src[e];
}

// ------- CSR gather with fused BN+ReLU (fp32 acc, fixed order => determ.) ----
// wave per node; half-wave per edge; lane o<FD/8 loads uint4 (8 bf16); 4-edge ILP.
template<int FD, bool BN>
__global__ __launch_bounds__(256) void gather_kernel(
    const u16* __restrict__ hsrc, const int* __restrict__ rowptr,
    const int* __restrict__ eidx, u16* __restrict__ aggb, int N,
    const long long* __restrict__ statsq, const float* __restrict__ gamma,
    const float* __restrict__ beta)
{
    constexpr int OCT = FD / 8;       // 24 (192) or 16 (128)
    __shared__ float scs[FD], shs[FD];
    const int t = threadIdx.x;
    if (BN) {
        if (t < FD) {
            float sc, sh;
            bn_params(statsq, gamma, beta, N, t, sc, sh);
            scs[t] = sc; shs[t] = sh;
        }
        __syncthreads();
    }
    const int lane = t & 63;
    const int half = lane >> 5;
    const int o    = lane & 31;
    const int n    = blockIdx.x * 4 + (t >> 6);
    if (n >= N) return;
    const bool act = (o < OCT);
    const int beg = rowptr[n], end = rowptr[n + 1];

    float scr[8], shr[8];
    if (BN && act) {
#pragma unroll
        for (int i = 0; i < 8; ++i) { scr[i] = scs[o * 8 + i]; shr[i] = shs[o * 8 + i]; }
    }

    float acc[8];
#pragma unroll
    for (int i = 0; i < 8; ++i) acc[i] = 0.f;

    auto consume = [&](uint4 v) {
        const u16* pu = (const u16*)&v;
#pragma unroll
        for (int i = 0; i < 8; ++i) {
            float f = b2f(pu[i]);
            if (BN) f = fmaxf(0.f, fmaf(f, scr[i], shr[i]));
            acc[i] += f;
        }
    };

    int j = beg + half;
    for (; j + 6 < end; j += 8) {         // 4 edges in flight per lane
        const int s0 = eidx[j],     s1 = eidx[j + 2];
        const int s2 = eidx[j + 4], s3 = eidx[j + 6];
        if (act) {
            const uint4 v0 = *(const uint4*)(hsrc + (size_t)s0 * FD + o * 8);
            const uint4 v1 = *(const uint4*)(hsrc + (size_t)s1 * FD + o * 8);
            const uint4 v2 = *(const uint4*)(hsrc + (size_t)s2 * FD + o * 8);
            const uint4 v3 = *(const uint4*)(hsrc + (size_t)s3 * FD + o * 8);
            consume(v0); consume(v1); consume(v2); consume(v3);
        }
    }
    for (; j < end; j += 2) {
        const int s0 = eidx[j];
        if (act) consume(*(const uint4*)(hsrc + (size_t)s0 * FD + o * 8));
    }
#pragma unroll
    for (int i = 0; i < 8; ++i) acc[i] += __shfl_xor(acc[i], 32);

    if (half == 0 && act) {
        u16 ov[8];
#pragma unroll
        for (int i = 0; i < 8; ++i) ov[i] = f2b(acc[i]);
        *(uint4*)(aggb + (size_t)n * FD + o * 8) = *(uint4*)ov;
    }
}

// -------- MFMA GEMM: 512 thr / 8 waves; block = 256 rows x 192 cols ----------
// Full B panel resident in LDS (staged once, global_load_lds); K-loop fully
// unrolled with depth-4 A register prefetch ring; BN+ReLU fused onto A2 reads.
// In-place safe: each wave reads only rows it later writes.
template<int K1, int K2, bool BN>
__global__ __launch_bounds__(512, 1) void gemm_mfma(
    const u16* __restrict__ A1, const u16* A2,
    const u16* __restrict__ Wb, const float* __restrict__ bias,
    u16* Hout, long long* __restrict__ statsq_out,
    const long long* __restrict__ statsq_in, const float* __restrict__ gamma,
    const float* __restrict__ beta, int N)
{
    constexpr int KC  = K1 + K2;
    constexpr int NC  = KC / 32;
    constexpr int NC1 = K1 / 32;
    __shared__ u16 bsh[HD * KC];          // 98KB (KC=256) / 147KB (KC=384)
    __shared__ float scs[K2], shs[K2];

    const int tid  = threadIdx.x;
    const int wave = tid >> 6, lane = tid & 63;
    const int c = lane & 15, kg = lane >> 4;
    const int row0 = blockIdx.x * 256 + wave * 32;

    {   // stage whole panel linearly (512 thr x 16B = 8KB per iter)
        constexpr int NST = (HD * KC) / (512 * 8);
        const u16* wsrc = Wb + tid * 8;
        u16* ldst = bsh + tid * 8;
#pragma unroll
        for (int i = 0; i < NST; ++i)
            async_cp16(wsrc + i * 4096, ldst + i * 4096);
    }
    if (BN) {
        if (tid < K2) {
            float sc, sh;
            bn_params(statsq_in, gamma, beta, N, tid, sc, sh);
            scs[tid] = sc; shs[tid] = sh;
        }
    }

    int arc[2];
#pragma unroll
    for (int m = 0; m < 2; ++m) {
        const int r = row0 + m * 16 + c;
        arc[m] = r < N ? r : N - 1;
    }

    f32x4 acc[2][12];
#pragma unroll
    for (int m = 0; m < 2; ++m)
#pragma unroll
        for (int f = 0; f < 12; ++f) acc[m][f] = (f32x4){0.f, 0.f, 0.f, 0.f};

    auto aload = [&](int ch, bf16x8* d) {
#pragma unroll
        for (int m = 0; m < 2; ++m) {
            const u16* p = (ch < NC1)
                ? (A1 + (size_t)arc[m] * K1 + ch * 32 + kg * 8)
                : (A2 + (size_t)arc[m] * K2 + (ch - NC1) * 32 + kg * 8);
            d[m] = *(const bf16x8*)p;
        }
    };

    bf16x8 ring[4][2];
#pragma unroll
    for (int p = 0; p < 4; ++p)
        if (p < NC) aload(p, ring[p]);

    __syncthreads();      // drains global_load_lds staging; scs/shs visible

#pragma unroll
    for (int ch = 0; ch < NC; ++ch) {
        bf16x8 a[2] = { ring[ch & 3][0], ring[ch & 3][1] };
        if (ch + 4 < NC) aload(ch + 4, ring[ch & 3]);   // refill slot
        if (BN && ch >= NC1) {                          // BN+ReLU on root frags
            const int k0 = (ch - NC1) * 32 + kg * 8;
            const float4 s0 = *(const float4*)&scs[k0];
            const float4 s1 = *(const float4*)&scs[k0 + 4];
            const float4 h0 = *(const float4*)&shs[k0];
            const float4 h1 = *(const float4*)&shs[k0 + 4];
            const float scv[8] = {s0.x,s0.y,s0.z,s0.w,s1.x,s1.y,s1.z,s1.w};
            const float shv[8] = {h0.x,h0.y,h0.z,h0.w,h1.x,h1.y,h1.z,h1.w};
#pragma unroll
            for (int m = 0; m < 2; ++m) {
                const u16* pa = (const u16*)&a[m];
                u16 tv[8];
#pragma unroll
                for (int i = 0; i < 8; ++i)
                    tv[i] = f2b(fmaxf(0.f, fmaf(b2f(pa[i]), scv[i], shv[i])));
                a[m] = *(bf16x8*)tv;
            }
        }
#pragma unroll
        for (int f = 0; f < 12; ++f) {
            const bf16x8 b = *(const bf16x8*)&bsh[ch * 6144 + f * 512 + kg * 128 + c * 8];
            acc[0][f] = __builtin_amdgcn_mfma_f32_16x16x32_bf16(a[0], b, acc[0][f], 0, 0, 0);
            acc[1][f] = __builtin_amdgcn_mfma_f32_16x16x32_bf16(a[1], b, acc[1][f], 0, 0, 0);
        }
    }

    // ---- epilogue: bias + store + BN partial sums ----
    float s1v[12], s2v[12];
#pragma unroll
    for (int f = 0; f < 12; ++f) { s1v[f] = 0.f; s2v[f] = 0.f; }

#pragma unroll
    for (int f = 0; f < 12; ++f) {
        const int col = f * 16 + c;
        const float bv = bias[col];
#pragma unroll
        for (int m = 0; m < 2; ++m)
#pragma unroll
            for (int r = 0; r < 4; ++r) {
                const int orow = row0 + m * 16 + kg * 4 + r;
                if (orow < N) {
                    const float v = acc[m][f][r] + bv;
                    s1v[f] += v;
                    s2v[f] += v * v;
                    Hout[(size_t)orow * HD + col] = f2b(v);
                }
            }
    }
#pragma unroll
    for (int f = 0; f < 12; ++f) {
        s1v[f] += __shfl_xor(s1v[f], 16); s1v[f] += __shfl_xor(s1v[f], 32);
        s2v[f] += __shfl_xor(s2v[f], 16); s2v[f] += __shfl_xor(s2v[f], 32);
    }
    __syncthreads();                       // all waves done with bsh
    float* red = (float*)bsh;              // reuse panel LDS: 2 x 8 x 192 floats
    if (kg == 0) {
#pragma unroll
        for (int f = 0; f < 12; ++f) {
            red[wave * HD + f * 16 + c]            = s1v[f];
            red[8 * HD + wave * HD + f * 16 + c]   = s2v[f];
        }
    }
    __syncthreads();
    if (tid < HD) {
        float a1 = 0.f, a2 = 0.f;
#pragma unroll
        for (int w = 0; w < 8; ++w) {
            a1 += red[w * HD + tid];
            a2 += red[8 * HD + w * HD + tid];
        }
        atomicAdd((unsigned long long*)&statsq_out[tid],
                  (unsigned long long)(long long)llrintf(a1 * STAT_S));
        atomicAdd((unsigned long long*)&statsq_out[HD + tid],
                  (unsigned long long)(long long)llrintf(a2 * STAT_S));
    }
}

// ------- parallel mean-pool partials with fused BN+ReLU -----------------------
__global__ __launch_bounds__(192) void pool_partial(const u16* __restrict__ h,
    const int* __restrict__ batch, int* __restrict__ gsumq, int N,
    const long long* __restrict__ statsq, const float* __restrict__ gamma,
    const float* __restrict__ beta)
{
    __shared__ float scs[HD], shs[HD];
    const int t = threadIdx.x;
    {
        float sc, sh;
        bn_params(statsq, gamma, beta, N, t, sc, sh);
        scs[t] = sc; shs[t] = sh;
    }
    __syncthreads();
    const int rl  = t / 24;        // 0..7
    const int oct = t % 24;        // 0..23
    const int r0  = blockIdx.x * 256;
    const int rend = (r0 + 256 < N) ? r0 + 256 : N;

    float scr[8], shr[8];
#pragma unroll
    for (int i = 0; i < 8; ++i) { scr[i] = scs[oct * 8 + i]; shr[i] = shs[oct * 8 + i]; }

    float facc[8];
#pragma unroll
    for (int i = 0; i < 8; ++i) facc[i] = 0.f;
    int cur = -1;

    for (int r = r0 + rl; r < rend; r += 8) {
        const int b = batch[r];
        if (b != cur) {
            if (cur >= 0) {
                int* q = gsumq + (size_t)cur * HD + oct * 8;
#pragma unroll
                for (int i = 0; i < 8; ++i)
                    atomicAdd(&q[i], __float2int_rn(facc[i] * POOL_S));
            }
#pragma unroll
            for (int i = 0; i < 8; ++i) facc[i] = 0.f;
            cur = b;
        }
        const uint4 pv = *(const uint4*)(h + (size_t)r * HD + oct * 8);
        const u16* pu = (const u16*)&pv;
#pragma unroll
        for (int i = 0; i < 8; ++i)
            facc[i] += fmaxf(0.f, fmaf(b2f(pu[i]), scr[i], shr[i]));
    }
    if (cur >= 0) {
        int* q = gsumq + (size_t)cur * HD + oct * 8;
#pragma unroll
        for (int i = 0; i < 8; ++i)
            atomicAdd(&q[i], __float2int_rn(facc[i] * POOL_S));
    }
}

// ------- MLP head: gv from fixed-point pool sums; coalesced weights -------
__global__ __launch_bounds__(192) void head_kernel(
    const int* __restrict__ gsumq, const int* __restrict__ batch, int N,
    const float* __restrict__ w1t, const float* __restrict__ b1,
    const float* __restrict__ w2t, const float* __restrict__ b2,
    const float* __restrict__ ow, const float* __restrict__ ob,
    float* __restrict__ out)
{
    __shared__ float gv[HD];
    __shared__ float h1[HD];
    __shared__ float h2[HD];
    const int g = blockIdx.x;
    const int t = threadIdx.x;

    int lo = 0, hi = N;
    while (lo < hi) { int m = (lo + hi) >> 1; if (batch[m] < g) lo = m + 1; else hi = m; }
    const int start = lo;
    hi = N;
    while (lo < hi) { int m = (lo + hi) >> 1; if (batch[m] < g + 1) lo = m + 1; else hi = m; }
    const int end = lo;
    const float cnt = fmaxf((float)(end - start), 1.0f);

    gv[t] = (float)gsumq[(size_t)g * HD + t] * POOL_IS / cnt;
    __syncthreads();
    {
        float acc = b1[t];
#pragma unroll 4
        for (int k = 0; k < HD; ++k)
            acc = fmaf(gv[k], w1t[k * HD + t], acc);
        h1[t] = fmaxf(acc, 0.f);
    }
    __syncthreads();
    {
        float acc = b2[t];
#pragma unroll 4
        for (int k = 0; k < HD; ++k)
            acc = fmaf(h1[k], w2t[k * HD + t], acc);
        h2[t] = acc * ow[t];
    }
    __syncthreads();
    if (t < 64) {
        float s = h2[t] + h2[t + 64] + h2[t + 128];
#pragma unroll
        for (int d = 1; d < 64; d <<= 1) s += __shfl_xor(s, d);
        if (t == 0) out[g] = s + ob[0];
    }
}

extern "C" void kernel_launch(void* const* d_in, const int* in_sizes, int n_in,
                              void* d_out, int out_size, void* d_ws, size_t ws_size,
                              hipStream_t stream)
{
    const float* x       = (const float*)d_in[0];
    const int*   ei      = (const int*)d_in[1];
    const int*   batch   = (const int*)d_in[2];
    const float* w_rel0  = (const float*)d_in[4];
    const float* b_rel0  = (const float*)d_in[5];
    const float* w_root0 = (const float*)d_in[6];
    const float* w_rel   = (const float*)d_in[7];
    const float* b_rel   = (const float*)d_in[8];
    const float* w_root  = (const float*)d_in[9];
    const float* bn_g    = (const float*)d_in[10];
    const float* bn_b    = (const float*)d_in[11];
    const float* hw1     = (const float*)d_in[12];
    const float* hb1     = (const float*)d_in[13];
    const float* hw2     = (const float*)d_in[14];
    const float* hb2     = (const float*)d_in[15];
    const float* ow      = (const float*)d_in[16];
    const float* ob      = (const float*)d_in[17];
    float* out = (float*)d_out;

    const int N = in_sizes[0] / FD0;
    const int E = in_sizes[1] / 2;
    const int* src = ei;
    const int* dst = ei + E;
    const int M = idiv(N, 256);

    char* ws = (char*)d_ws;
    size_t off = 0;
    u16*   xb   = (u16*)(ws + off);   off += (size_t)N * FD0 * 2;
    u16*   h    = (u16*)(ws + off);   off += (size_t)N * HD * 2;
    u16*   aggb = (u16*)(ws + off);   off += (size_t)N * HD * 2;
    u16*   wp0  = (u16*)(ws + off);   off += (size_t)HD * 2 * FD0 * 2;
    u16*   wp123= (u16*)(ws + off);   off += (size_t)3 * HD * 2 * HD * 2;
    off = (off + 15) & ~(size_t)15;
    float* w1t = (float*)(ws + off); off += (size_t)HD * HD * 4;
    float* w2t = (float*)(ws + off); off += (size_t)HD * HD * 4;
    long long* statsq4 = (long long*)(ws + off); off += 4 * 2 * HD * sizeof(long long);
    int*   gsumq  = (int*)(ws + off); off += (size_t)NG * HD * 4;   // adjacent to statsq4
    int*   rowptr = (int*)(ws + off); off += (size_t)(N + 1) * 4;
    int*   deg    = (int*)(ws + off); off += (size_t)N * 4;
    int*   psum   = (int*)(ws + off); off += (size_t)M * 4;
    int*   eidx   = (int*)(ws + off); off += (size_t)E * 4;

    const dim3 b256(256), b512(512), b192(192);

    // ---- prep: convert, pack+transpose, zero stats+gsum, CSR build
    convert_bf16<<<idiv(N * FD0 / 4, 256), b256, 0, stream>>>(x, xb, N * FD0 / 4);
    pack_fuse<<<idiv(HD * 2 * FD0 + 3 * HD * 2 * HD + 2 * HD * HD, 256), b256, 0,
                stream>>>(w_rel0, w_root0, w_rel, w_root, hw1, hw2,
                          wp0, wp123, w1t, w2t);
    hipMemsetAsync(statsq4, 0, 4 * 2 * HD * sizeof(long long) + (size_t)NG * HD * 4,
                   stream);
    hipMemsetAsync(deg, 0, (size_t)N * sizeof(int), stream);
    hist_kernel<<<idiv(E, 256), b256, 0, stream>>>(dst, deg, E);
    scan_partial<<<M, b256, 0, stream>>>(deg, psum, N);
    scan_small<<<1, b256, 0, stream>>>(psum, M);
    scan_expand<<<M, b256, 0, stream>>>(deg, psum, rowptr, N, E);  // deg -> cursor
    fill_kernel<<<idiv(E, 256), b256, 0, stream>>>(src, dst, deg, eidx, E);

    // ---- layer 0 (K=128+128): raw x features
    gather_kernel<FD0, false><<<idiv(N, 4), b256, 0, stream>>>(
        xb, rowptr, eidx, aggb, N, nullptr, nullptr, nullptr);
    gemm_mfma<FD0, FD0, false><<<idiv(N, 256), b512, 0, stream>>>(
        aggb, xb, wp0, b_rel0, h, statsq4, nullptr, nullptr, nullptr, N);

    // ---- layers 1..3 (K=192+192): BN+ReLU fused into consumers; gemm in-place
    for (int i = 0; i < 3; ++i) {
        const long long* sin  = statsq4 + (size_t)i * 2 * HD;
        long long*       sout = statsq4 + (size_t)(i + 1) * 2 * HD;
        const float* g = bn_g + (size_t)i * HD;
        const float* b = bn_b + (size_t)i * HD;
        gather_kernel<HD, true><<<idiv(N, 4), b256, 0, stream>>>(
            h, rowptr, eidx, aggb, N, sin, g, b);
        gemm_mfma<HD, HD, true><<<idiv(N, 256), b512, 0, stream>>>(
            aggb, h, wp123 + (size_t)i * HD * 2 * HD,
            b_rel + (size_t)i * HD, h, sout, sin, g, b, N);
    }

    // ---- pool partials (BN(3) fused) + tiny head
    pool_partial<<<idiv(N, 256), b192, 0, stream>>>(
        h, batch, gsumq, N, statsq4 + 3 * 2 * (size_t)HD,
        bn_g + 3 * (size_t)HD, bn_b + 3 * (size_t)HD);
    head_kernel<<<NG, b192, 0, stream>>>(gsumq, batch, N, w1t, hb1, w2t, hb2,
                                         ow, ob, out);
}